// Round 1
// baseline (60.692 us; speedup 1.0000x reference)
//
#include <hip/hip_runtime.h>
#include <cstdint>

#define M_TOT 8192
#define K_PTS 32
#define NCH 64
#define MT 16   // m values per block

// Precompute A = (Wq^T Wk) * log2(e)/8  (3x3)  and  u = (Wk^T bq) * log2(e)/8 (3)
// score_for_exp2[k][j] = x_k . (A x_j) + u . x_j   (+ terms constant in j, dropped:
// they cancel in softmax over j).
__global__ void setup_kernel(const float* __restrict__ Wq, const float* __restrict__ bq,
                             const float* __restrict__ Wk, const float* __restrict__ bk,
                             float* __restrict__ ws) {
  if (threadIdx.x == 0 && blockIdx.x == 0) {
    const float scale = 1.4426950408889634f / 8.0f; // log2(e) / sqrt(CH)
    float A[9] = {0,0,0,0,0,0,0,0,0};
    float u[3] = {0,0,0};
    for (int o = 0; o < NCH; ++o) {
      float wq0 = Wq[o*3+0], wq1 = Wq[o*3+1], wq2 = Wq[o*3+2];
      float wk0 = Wk[o*3+0], wk1 = Wk[o*3+1], wk2 = Wk[o*3+2];
      float bqo = bq[o];
      A[0] += wq0*wk0; A[1] += wq0*wk1; A[2] += wq0*wk2;
      A[3] += wq1*wk0; A[4] += wq1*wk1; A[5] += wq1*wk2;
      A[6] += wq2*wk0; A[7] += wq2*wk1; A[8] += wq2*wk2;
      u[0] += bqo*wk0; u[1] += bqo*wk1; u[2] += bqo*wk2;
    }
    for (int i = 0; i < 9; ++i) ws[i] = A[i] * scale;
    for (int i = 0; i < 3; ++i) ws[9+i] = u[i] * scale;
  }
}

__global__ __launch_bounds__(512) void attn_main(const float* __restrict__ xyz,
                                                 const float* __restrict__ Wv,
                                                 const float* __restrict__ bv,
                                                 const float* __restrict__ ws,
                                                 float* __restrict__ out) {
  // x_lds: [m][k*3+c], row stride 97 (pad) to break 96-float power-pattern conflicts
  __shared__ __align__(16) float x_lds[MT*97 + 4];
  __shared__ __align__(16) float gh_lds[MT*128]; // [m][j*4 + {g0,g1,g2,h}]
  __shared__ __align__(16) float y_lds[MT*128];  // [m][k*4 + {y0,y1,y2,_}]

  const int t = threadIdx.x;
  const int b = blockIdx.x >> 9;          // grid = 4 * 512
  const int m0 = (blockIdx.x & 511) * MT;

  const float* xb = xyz + ((size_t)b * 3 * K_PTS) * M_TOT + m0;

  // ---- Phase L: load 3*32*16 = 1536 floats, coalesced (16-float runs per (c,k) row)
  #pragma unroll
  for (int p = 0; p < 3; ++p) {
    int i = t + p * 512;
    int mo = i & (MT - 1);
    int r  = i >> 4;              // r = c*32 + k, 0..95
    float val = xb[(size_t)r * M_TOT + mo];
    int k = r & 31, c = r >> 5;
    x_lds[mo*97 + k*3 + c] = val;
  }

  // uniform scalar loads of the tiny precomputed matrices
  float A00 = ws[0], A01 = ws[1], A02 = ws[2];
  float A10 = ws[3], A11 = ws[4], A12 = ws[5];
  float A20 = ws[6], A21 = ws[7], A22 = ws[8];
  float u0  = ws[9], u1  = ws[10], u2 = ws[11];

  __syncthreads();

  // ---- Phase 0: per (m,j): g = A x_j, h = u . x_j
  {
    int m = t >> 5, j = t & 31;
    float x0 = x_lds[m*97 + j*3 + 0];
    float x1 = x_lds[m*97 + j*3 + 1];
    float x2 = x_lds[m*97 + j*3 + 2];
    float g0 = fmaf(A02, x2, fmaf(A01, x1, A00 * x0));
    float g1 = fmaf(A12, x2, fmaf(A11, x1, A10 * x0));
    float g2 = fmaf(A22, x2, fmaf(A21, x1, A20 * x0));
    float h  = fmaf(u2,  x2, fmaf(u1,  x1, u0  * x0));
    *(float4*)&gh_lds[m*128 + j*4] = make_float4(g0, g1, g2, h);
  }
  __syncthreads();

  // ---- Phase 1: per (m,k): 32 scores, softmax, y_k = sum_j attn * x_j (3-vector)
  {
    int m = t >> 5, k = t & 31;
    float xk0 = x_lds[m*97 + k*3 + 0];
    float xk1 = x_lds[m*97 + k*3 + 1];
    float xk2 = x_lds[m*97 + k*3 + 2];
    float s[32];
    #pragma unroll
    for (int j = 0; j < 32; ++j) {
      float4 gh = *(const float4*)&gh_lds[m*128 + j*4]; // broadcast across half-wave
      s[j] = fmaf(xk0, gh.x, fmaf(xk1, gh.y, fmaf(xk2, gh.z, gh.w)));
    }
    float mx = s[0];
    #pragma unroll
    for (int j = 1; j < 32; ++j) mx = fmaxf(mx, s[j]);
    float sum = 0.f, y0 = 0.f, y1 = 0.f, y2 = 0.f;
    #pragma unroll
    for (int j = 0; j < 32; ++j) {
      float p = exp2f(s[j] - mx);
      sum += p;
      y0 = fmaf(p, x_lds[m*97 + j*3 + 0], y0);
      y1 = fmaf(p, x_lds[m*97 + j*3 + 1], y1);
      y2 = fmaf(p, x_lds[m*97 + j*3 + 2], y2);
    }
    float inv = 1.0f / sum;
    *(float4*)&y_lds[m*128 + k*4] = make_float4(y0*inv, y1*inv, y2*inv, 0.f);
  }
  __syncthreads();

  // ---- Phase 2: per thread (k = t>>4, 4 channels c4 = (t&15)*4), loop over m.
  // A wave's float4 stores cover 1 KB contiguous output -> fully coalesced.
  {
    int k  = t >> 4;
    int c4 = (t & 15) * 4;
    float w00 = Wv[(c4+0)*3+0], w01 = Wv[(c4+0)*3+1], w02 = Wv[(c4+0)*3+2], b0 = bv[c4+0];
    float w10 = Wv[(c4+1)*3+0], w11 = Wv[(c4+1)*3+1], w12 = Wv[(c4+1)*3+2], b1 = bv[c4+1];
    float w20 = Wv[(c4+2)*3+0], w21 = Wv[(c4+2)*3+1], w22 = Wv[(c4+2)*3+2], b2 = bv[c4+2];
    float w30 = Wv[(c4+3)*3+0], w31 = Wv[(c4+3)*3+1], w32 = Wv[(c4+3)*3+2], b3 = bv[c4+3];
    float* op = out + (((size_t)b * M_TOT + m0) * K_PTS + k) * NCH + c4;
    #pragma unroll
    for (int m = 0; m < MT; ++m) {
      float4 y = *(const float4*)&y_lds[m*128 + k*4];
      float4 r;
      r.x = fmaxf(0.f, fmaf(w00, y.x, fmaf(w01, y.y, fmaf(w02, y.z, b0))));
      r.y = fmaxf(0.f, fmaf(w10, y.x, fmaf(w11, y.y, fmaf(w12, y.z, b1))));
      r.z = fmaxf(0.f, fmaf(w20, y.x, fmaf(w21, y.y, fmaf(w22, y.z, b2))));
      r.w = fmaxf(0.f, fmaf(w30, y.x, fmaf(w31, y.y, fmaf(w32, y.z, b3))));
      *(float4*)(op + (size_t)m * (K_PTS * NCH)) = r;
    }
  }
}

extern "C" void kernel_launch(void* const* d_in, const int* in_sizes, int n_in,
                              void* d_out, int out_size, void* d_ws, size_t ws_size,
                              hipStream_t stream) {
  const float* xyz = (const float*)d_in[0];
  const float* Wq  = (const float*)d_in[1];
  const float* bq  = (const float*)d_in[2];
  const float* Wk  = (const float*)d_in[3];
  const float* bk  = (const float*)d_in[4];
  const float* Wv  = (const float*)d_in[5];
  const float* bv  = (const float*)d_in[6];
  float* out = (float*)d_out;
  float* ws  = (float*)d_ws;

  setup_kernel<<<1, 64, 0, stream>>>(Wq, bq, Wk, bk, ws);
  attn_main<<<2048, 512, 0, stream>>>(xyz, Wv, bv, ws, out);
}